// Round 7
// baseline (87.718 us; speedup 1.0000x reference)
//
#include <hip/hip_runtime.h>
#include <math.h>

#define NU 100000
#define NI 50000
#define DK 256      // DU == DI
#define EN 128      // E
#define BB 8192
#define TT 24

typedef short short8 __attribute__((ext_vector_type(8)));
typedef float f32x4  __attribute__((ext_vector_type(4)));

// ---- d_ws layout (bytes) ----
#define WPACK_SHORTS 114688
#define WP_OFF     0
#define OWNER_OFF  229376                 // 100000 ints
#define NTAB_OFF   629376                 // 50000*128 bf16 = 12.8 MB
#define NPART_OFF  13429376               // 8192*128 f32  = 4 MB

// wpack element offsets (bf16 shorts, all [N][K] k-contiguous)
#define OFF_IWT   0        // 128x256
#define OFF_UWT   32768    // 128x256
#define OFF_AW1UT 65536    // 128x128 (aW1 rows 0..127   -> neigh part)
#define OFF_AW1LT 81920    // 128x128 (aW1 rows 128..255 -> node part)
#define OFF_AW2T  98304    // 128x128

#define NBLK_NEIGH 782     // ceil(NI/64)
#define NBLK_NF    128     // BB/64
#define NBLK_PACK  448     // WPACK_SHORTS/256
#define ATTN_BLKS  (BB / 2)

__device__ __forceinline__ unsigned short f2b(float x) {
    unsigned int u = __float_as_uint(x);
    u = (u + 0x7FFFu + ((u >> 16) & 1u)) >> 16;   // RNE, finite inputs
    return (unsigned short)u;
}
__device__ __forceinline__ float b2f(unsigned short v) {
    return __uint_as_float(((unsigned int)v) << 16);
}

#define MFMA(a, b, c) __builtin_amdgcn_mfma_f32_16x16x32_bf16((a), (b), (c), 0, 0, 0)
#define LDROW(buf, stride, row, k) \
    (*reinterpret_cast<const short8*>(reinterpret_cast<const char*>(buf) + (row) * (stride) + (k) * 2))

// ---- K1 (tiny): pack weights + owner reset ----
__global__ __launch_bounds__(256)
void prep_kernel(const int* __restrict__ nodes,
                 const float* __restrict__ uW, const float* __restrict__ iW,
                 const float* __restrict__ aW1, const float* __restrict__ aW2,
                 short* __restrict__ wp, int* __restrict__ owner)
{
    if (blockIdx.x < NBLK_PACK) {
        int i = blockIdx.x * 256 + threadIdx.x;
        float v;
        if (i < 32768)      { int j = i;         int n = j >> 8, k = j & 255; v = iW[k * EN + n]; }
        else if (i < 65536) { int j = i - 32768; int n = j >> 8, k = j & 255; v = uW[k * EN + n]; }
        else if (i < 81920) { int j = i - 65536; int n = j >> 7, k = j & 127; v = aW1[k * EN + n]; }
        else if (i < 98304) { int j = i - 81920; int n = j >> 7, k = j & 127; v = aW1[(128 + k) * EN + n]; }
        else                { int j = i - 98304; int n = j >> 7, k = j & 127; v = aW2[k * EN + n]; }
        wp[i] = (short)f2b(v);
    } else {
        int b = (blockIdx.x - NBLK_PACK) * 256 + threadIdx.x;
        if (b < BB) owner[nodes[b]] = -1;
    }
}

// ---- K2: union kernel: blocks [0,782) neighs table; [782,910) nf/npart (+owner max) ----
__global__ __launch_bounds__(256, 4)
void embed_kernel(const int* __restrict__ nodes,
                  const float* __restrict__ u_weight, const float* __restrict__ i_weight,
                  const float* __restrict__ ub, const float* __restrict__ ib,
                  const float* __restrict__ ab1,
                  const short* __restrict__ wp, int* __restrict__ owner,
                  short* __restrict__ ntab, float* __restrict__ out_nf,
                  float* __restrict__ npart)
{
    __shared__ __align__(16) char smem[33792];   // A-staging (528B x 64 rows); overlaid by outputs
    __shared__ int sNd[64];

    const int tid = threadIdx.x;
    const int l = tid & 63, lr = l & 15, lq = l >> 4, n0 = (tid >> 6) * 32;
    const int kA = lq * 8, nc0 = n0 + lr, nc1 = n0 + 16 + lr;

    if (blockIdx.x < NBLK_NEIGH) {
        // ======== neighs path: ntab[r] = bf16(i_weight[r] @ iW + ib) ========
        const int r0 = blockIdx.x * 64;
        const int nrows = (NI - r0 < 64) ? (NI - r0) : 64;

        for (int task = tid; task < 64 * 32; task += 256) {
            int row = task >> 5, c = task & 31;
            if (row < nrows) {
                const float* src = i_weight + (size_t)(r0 + row) * DK + c * 8;
                float4 f0 = *(const float4*)src;
                float4 f1 = *(const float4*)(src + 4);
                short8 o;
                o[0]=f2b(f0.x); o[1]=f2b(f0.y); o[2]=f2b(f0.z); o[3]=f2b(f0.w);
                o[4]=f2b(f1.x); o[5]=f2b(f1.y); o[6]=f2b(f1.z); o[7]=f2b(f1.w);
                *reinterpret_cast<short8*>(smem + row * 528 + c * 16) = o;
            }
        }
        __syncthreads();

        const short* iWt = wp + OFF_IWT;
        f32x4 acc[4][2];
        #pragma unroll
        for (int m = 0; m < 4; ++m) { acc[m][0] = {0.f,0.f,0.f,0.f}; acc[m][1] = {0.f,0.f,0.f,0.f}; }
        #pragma unroll
        for (int ks = 0; ks < 8; ++ks) {
            int k = ks * 32 + kA;
            short8 w0 = *reinterpret_cast<const short8*>(iWt + nc0 * DK + k);
            short8 w1 = *reinterpret_cast<const short8*>(iWt + nc1 * DK + k);
            #pragma unroll
            for (int m = 0; m < 4; ++m) {
                short8 a = LDROW(smem, 528, m * 16 + lr, k);
                acc[m][0] = MFMA(a, w0, acc[m][0]);
                acc[m][1] = MFMA(a, w1, acc[m][1]);
            }
        }
        __syncthreads();   // all reads of A done; overlay output tile (264B stride)
        {
            float ib0 = ib[nc0], ib1 = ib[nc1];
            #pragma unroll
            for (int m = 0; m < 4; ++m)
                #pragma unroll
                for (int nt = 0; nt < 2; ++nt) {
                    int n = nt ? nc1 : nc0;
                    float bv = nt ? ib1 : ib0;
                    #pragma unroll
                    for (int r = 0; r < 4; ++r) {
                        int row = m * 16 + lq * 4 + r;
                        *reinterpret_cast<short*>(smem + row * 264 + n * 2)
                            = (short)f2b(acc[m][nt][r] + bv);
                    }
                }
        }
        __syncthreads();
        for (int g = tid; g < nrows * 16; g += 256) {
            int row = g >> 4, s = g & 15;
            short8 v = *reinterpret_cast<const short8*>(smem + row * 264 + s * 16);
            *reinterpret_cast<short8*>(ntab + (size_t)(r0 + row) * EN + s * 8) = v;
        }
    } else {
        // ======== nf path: out_nf + npart for 64 batch rows; also owner atomicMax ========
        const int bblk = blockIdx.x - NBLK_NEIGH;
        const int r0 = bblk * 64;
        {
            int bq = bblk * 256 + tid;
            if (bq < BB) atomicMax(&owner[nodes[bq]], bq);
        }
        if (tid < 64) sNd[tid] = nodes[r0 + tid];
        __syncthreads();

        for (int task = tid; task < 64 * 32; task += 256) {
            int row = task >> 5, c = task & 31;
            const float* src = u_weight + (size_t)sNd[row] * DK + c * 8;
            float4 f0 = *(const float4*)src;
            float4 f1 = *(const float4*)(src + 4);
            short8 o;
            o[0]=f2b(f0.x); o[1]=f2b(f0.y); o[2]=f2b(f0.z); o[3]=f2b(f0.w);
            o[4]=f2b(f1.x); o[5]=f2b(f1.y); o[6]=f2b(f1.z); o[7]=f2b(f1.w);
            *reinterpret_cast<short8*>(smem + row * 528 + c * 16) = o;
        }
        __syncthreads();

        const short* uWt   = wp + OFF_UWT;
        const short* aW1Lt = wp + OFF_AW1LT;

        f32x4 acc[4][2];
        #pragma unroll
        for (int m = 0; m < 4; ++m) { acc[m][0] = {0.f,0.f,0.f,0.f}; acc[m][1] = {0.f,0.f,0.f,0.f}; }
        #pragma unroll
        for (int ks = 0; ks < 8; ++ks) {
            int k = ks * 32 + kA;
            short8 w0 = *reinterpret_cast<const short8*>(uWt + nc0 * DK + k);
            short8 w1 = *reinterpret_cast<const short8*>(uWt + nc1 * DK + k);
            #pragma unroll
            for (int m = 0; m < 4; ++m) {
                short8 a = LDROW(smem, 528, m * 16 + lr, k);
                acc[m][0] = MFMA(a, w0, acc[m][0]);
                acc[m][1] = MFMA(a, w1, acc[m][1]);
            }
        }
        __syncthreads();   // A reads done; overlay bf16 nf tile (272B stride)
        {
            float b0v = ub[nc0], b1v = ub[nc1];
            #pragma unroll
            for (int m = 0; m < 4; ++m)
                #pragma unroll
                for (int nt = 0; nt < 2; ++nt) {
                    int n = nt ? nc1 : nc0;
                    float bv = nt ? b1v : b0v;
                    #pragma unroll
                    for (int r = 0; r < 4; ++r) {
                        int row = m * 16 + lq * 4 + r;
                        float v = acc[m][nt][r] + bv;
                        out_nf[(size_t)(r0 + row) * EN + n] = v;
                        *reinterpret_cast<short*>(smem + row * 272 + n * 2) = (short)f2b(v);
                    }
                }
        }
        __syncthreads();

        f32x4 ap[4][2];
        #pragma unroll
        for (int m = 0; m < 4; ++m) { ap[m][0] = {0.f,0.f,0.f,0.f}; ap[m][1] = {0.f,0.f,0.f,0.f}; }
        #pragma unroll
        for (int ks = 0; ks < 4; ++ks) {
            int k = ks * 32 + kA;
            short8 w0 = *reinterpret_cast<const short8*>(aW1Lt + nc0 * EN + k);
            short8 w1 = *reinterpret_cast<const short8*>(aW1Lt + nc1 * EN + k);
            #pragma unroll
            for (int m = 0; m < 4; ++m) {
                short8 a = LDROW(smem, 272, m * 16 + lr, k);
                ap[m][0] = MFMA(a, w0, ap[m][0]);
                ap[m][1] = MFMA(a, w1, ap[m][1]);
            }
        }
        {
            float b0v = ab1[nc0], b1v = ab1[nc1];
            #pragma unroll
            for (int m = 0; m < 4; ++m)
                #pragma unroll
                for (int nt = 0; nt < 2; ++nt) {
                    int n = nt ? nc1 : nc0;
                    float bv = nt ? b1v : b0v;
                    #pragma unroll
                    for (int r = 0; r < 4; ++r) {
                        int row = m * 16 + lq * 4 + r;
                        npart[(size_t)(r0 + row) * EN + n] = ap[m][nt][r] + bv;
                    }
                }
        }
    }
}

// ---- K3: attn; zero of non-batch out_embed rows moved to the TAIL ----
__global__ __launch_bounds__(256, 4)
void attn_kernel(const int* __restrict__ nodes, const int* __restrict__ neigh_idx,
                 const float* __restrict__ ab2, const float* __restrict__ aW3,
                 const float* __restrict__ ab3, const short* __restrict__ wp,
                 const short* __restrict__ ntab, const float* __restrict__ npart,
                 const int* __restrict__ owner, float* __restrict__ out_embed)
{
    __shared__ __align__(16) short sNg[48 * 136];  // 13056 B, 272B stride
    __shared__ __align__(16) short sH1[48 * 136];  // 13056 B
    __shared__ float sNp[256];
    __shared__ float sLogP[4][48];
    __shared__ float sAtt[48];

    const int tid = threadIdx.x;
    const int b0  = blockIdx.x * 2;

    // hoisted scatter metadata (block-uniform -> scalar loads)
    const int node0 = nodes[b0], node1 = nodes[b0 + 1];
    const int own0  = owner[node0], own1 = owner[node1];

    sNp[tid] = npart[(size_t)b0 * EN + tid];

    // gather 48 neighbor rows (256B bf16 each); idx loaded inline (no sIdx barrier)
    for (int task = tid; task < 48 * 16; task += 256) {
        int row = task >> 4, s = task & 15;
        int idx = neigh_idx[b0 * TT + row];
        short8 v = *reinterpret_cast<const short8*>(ntab + (size_t)idx * EN + s * 8);
        *reinterpret_cast<short8*>(reinterpret_cast<char*>(sNg) + row * 272 + s * 16) = v;
    }
    __syncthreads();

    const int l = tid & 63, lr = l & 15, lq = l >> 4;
    const int wid = tid >> 6, n0 = wid * 32;
    const int kA = lq * 8, nc0 = n0 + lr, nc1 = n0 + 16 + lr;
    const short* aW1Ut = wp + OFF_AW1UT;
    const short* aW2t  = wp + OFF_AW2T;

    // h1 = relu(neighs @ aW1U + npart)
    f32x4 a1[3][2];
    #pragma unroll
    for (int m = 0; m < 3; ++m) { a1[m][0] = {0.f,0.f,0.f,0.f}; a1[m][1] = {0.f,0.f,0.f,0.f}; }
    #pragma unroll
    for (int ks = 0; ks < 4; ++ks) {
        int k = ks * 32 + kA;
        short8 w0 = *reinterpret_cast<const short8*>(aW1Ut + nc0 * EN + k);
        short8 w1 = *reinterpret_cast<const short8*>(aW1Ut + nc1 * EN + k);
        #pragma unroll
        for (int m = 0; m < 3; ++m) {
            short8 a = LDROW(sNg, 272, m * 16 + lr, k);
            a1[m][0] = MFMA(a, w0, a1[m][0]);
            a1[m][1] = MFMA(a, w1, a1[m][1]);
        }
    }
    #pragma unroll
    for (int m = 0; m < 3; ++m)
        #pragma unroll
        for (int nt = 0; nt < 2; ++nt) {
            int n = nt ? nc1 : nc0;
            #pragma unroll
            for (int r = 0; r < 4; ++r) {
                int row = m * 16 + lq * 4 + r;
                int g = (row >= TT) ? 1 : 0;
                float v = fmaxf(a1[m][nt][r] + sNp[g * EN + n], 0.f);
                *reinterpret_cast<short*>(reinterpret_cast<char*>(sH1) + row * 272 + n * 2)
                    = (short)f2b(v);
            }
        }
    __syncthreads();

    // h2 = relu(h1 @ aW2 + ab2); logits accumulated in-register
    f32x4 a2[3][2];
    #pragma unroll
    for (int m = 0; m < 3; ++m) { a2[m][0] = {0.f,0.f,0.f,0.f}; a2[m][1] = {0.f,0.f,0.f,0.f}; }
    #pragma unroll
    for (int ks = 0; ks < 4; ++ks) {
        int k = ks * 32 + kA;
        short8 w0 = *reinterpret_cast<const short8*>(aW2t + nc0 * EN + k);
        short8 w1 = *reinterpret_cast<const short8*>(aW2t + nc1 * EN + k);
        #pragma unroll
        for (int m = 0; m < 3; ++m) {
            short8 a = LDROW(sH1, 272, m * 16 + lr, k);
            a2[m][0] = MFMA(a, w0, a2[m][0]);
            a2[m][1] = MFMA(a, w1, a2[m][1]);
        }
    }
    {
        float b0v = ab2[nc0], b1v = ab2[nc1];
        float w3a = aW3[nc0], w3b = aW3[nc1];
        #pragma unroll
        for (int m = 0; m < 3; ++m) {
            float lp[4];
            #pragma unroll
            for (int r = 0; r < 4; ++r) {
                float v0 = fmaxf(a2[m][0][r] + b0v, 0.f);
                float v1 = fmaxf(a2[m][1][r] + b1v, 0.f);
                lp[r] = v0 * w3a + v1 * w3b;
            }
            #pragma unroll
            for (int r = 0; r < 4; ++r) {
                float v = lp[r];
                v += __shfl_xor(v, 1, 16);
                v += __shfl_xor(v, 2, 16);
                v += __shfl_xor(v, 4, 16);
                v += __shfl_xor(v, 8, 16);
                if (lr == 0) sLogP[wid][m * 16 + lq * 4 + r] = v;
            }
        }
    }
    __syncthreads();

    // merged logit-reduce + softmax in wave 0 (shfl lane-remap, no sLog round-trip)
    if (tid < 64) {
        float s48 = 0.f;
        if (tid < 48)
            s48 = sLogP[0][tid] + sLogP[1][tid] + sLogP[2][tid] + sLogP[3][tid] + ab3[0];
        int g = tid >> 5, tt = tid & 31;
        float v = __shfl(s48, g * 24 + tt, 64);
        v = (tt < TT) ? v : -1e30f;
        float mx = v;
        #pragma unroll
        for (int d = 16; d > 0; d >>= 1) mx = fmaxf(mx, __shfl_xor(mx, d, 32));
        float p = (tt < TT) ? __expf(v - mx) : 0.f;
        float s = p;
        #pragma unroll
        for (int d = 16; d > 0; d >>= 1) s += __shfl_xor(s, d, 32);
        if (tt < TT) sAtt[g * TT + tt] = p / s;
    }
    __syncthreads();

    // agg + scatter
    {
        int g = tid >> 7, e = tid & 127;
        float a = 0.f;
        #pragma unroll
        for (int t = 0; t < TT; ++t) {
            unsigned short nv = *reinterpret_cast<const unsigned short*>(
                reinterpret_cast<const char*>(sNg) + (g * TT + t) * 272 + e * 2);
            a += sAtt[g * TT + t] * b2f(nv);
        }
        int node = g ? node1 : node0;
        int own  = g ? own1  : own0;
        if (own == b0 + g)
            out_embed[(size_t)node * EN + e] = a;
    }

    // ---- tail zero: rows with owner<0 are never scatter-written; write-sets disjoint.
    // Early generations' store flush hides under later generations' compute.
    {
        float4* embed4 = (float4*)out_embed;
        const int n16 = NU * EN / 4;
        const int gsz = ATTN_BLKS * 256;
        float4 z = {0.f, 0.f, 0.f, 0.f};
        for (int i = blockIdx.x * 256 + tid; i < n16; i += gsz) {
            if (owner[i >> 5] < 0) embed4[i] = z;
        }
    }
}

extern "C" void kernel_launch(void* const* d_in, const int* in_sizes, int n_in,
                              void* d_out, int out_size, void* d_ws, size_t ws_size,
                              hipStream_t stream) {
    const int*   nodes     = (const int*)d_in[0];
    const int*   neigh_idx = (const int*)d_in[1];
    const float* u_weight  = (const float*)d_in[2];
    const float* i_weight  = (const float*)d_in[3];
    const float* uW  = (const float*)d_in[4];
    const float* ub  = (const float*)d_in[5];
    const float* iW  = (const float*)d_in[6];
    const float* ib  = (const float*)d_in[7];
    const float* aW1 = (const float*)d_in[8];
    const float* ab1 = (const float*)d_in[9];
    const float* aW2 = (const float*)d_in[10];
    const float* ab2 = (const float*)d_in[11];
    const float* aW3 = (const float*)d_in[12];
    const float* ab3 = (const float*)d_in[13];

    float* out_nf    = (float*)d_out;
    float* out_embed = out_nf + (size_t)BB * EN;

    char*  ws    = (char*)d_ws;
    short* wpack = (short*)(ws + WP_OFF);
    int*   owner = (int*)(ws + OWNER_OFF);
    short* ntab  = (short*)(ws + NTAB_OFF);
    float* npart = (float*)(ws + NPART_OFF);

    prep_kernel<<<NBLK_PACK + 32, 256, 0, stream>>>(nodes, uW, iW, aW1, aW2, wpack, owner);
    embed_kernel<<<NBLK_NEIGH + NBLK_NF, 256, 0, stream>>>(
        nodes, u_weight, i_weight, ub, ib, ab1, wpack, owner, ntab, out_nf, npart);
    attn_kernel<<<ATTN_BLKS, 256, 0, stream>>>(nodes, neigh_idx, ab2, aW3, ab3,
                                               wpack, ntab, npart, owner, out_embed);
}

// Round 8
// 79.783 us; speedup vs baseline: 1.0995x; 1.0995x over previous
//
#include <hip/hip_runtime.h>
#include <math.h>

#define NU 100000
#define NI 50000
#define DK 256      // DU == DI
#define EN 128      // E
#define BB 8192
#define TT 24

typedef short short8 __attribute__((ext_vector_type(8)));
typedef float f32x4  __attribute__((ext_vector_type(4)));

// ---- d_ws layout (bytes) ----
#define WPACK_SHORTS 114688
#define WP_OFF     0
#define OWNER_OFF  229376                 // 100000 ints
#define NTAB_OFF   629376                 // 50000*128 bf16 = 12.8 MB
#define NPART_OFF  13429376               // 8192*128 f32  = 4 MB

// wpack element offsets (bf16 shorts, all [N][K] k-contiguous)
#define OFF_IWT   0        // 128x256
#define OFF_UWT   32768    // 128x256
#define OFF_AW1UT 65536    // 128x128 (aW1 rows 0..127   -> neigh part)
#define OFF_AW1LT 81920    // 128x128 (aW1 rows 128..255 -> node part)
#define OFF_AW2T  98304    // 128x128

#define NBLK_NEIGH 782     // ceil(NI/64)
#define NBLK_NF    128     // BB/64
#define NBLK_PACK  448     // WPACK_SHORTS/256
#define GGA 4              // batch rows per attn block
#define ATTN_BLKS  (BB / GGA)

__device__ __forceinline__ unsigned short f2b(float x) {
    unsigned int u = __float_as_uint(x);
    u = (u + 0x7FFFu + ((u >> 16) & 1u)) >> 16;   // RNE, finite inputs
    return (unsigned short)u;
}
__device__ __forceinline__ float b2f(unsigned short v) {
    return __uint_as_float(((unsigned int)v) << 16);
}
__device__ __forceinline__ unsigned int cvtpk_bf16(float lo, float hi) {
    unsigned int r;
    asm("v_cvt_pk_bf16_f32 %0, %1, %2" : "=v"(r) : "v"(lo), "v"(hi));
    return r;
}

#define MFMA(a, b, c) __builtin_amdgcn_mfma_f32_16x16x32_bf16((a), (b), (c), 0, 0, 0)
#define LDROW(buf, stride, row, k) \
    (*reinterpret_cast<const short8*>(reinterpret_cast<const char*>(buf) + (row) * (stride) + (k) * 2))

// ---- K1 (tiny): pack weights + owner reset ----
__global__ __launch_bounds__(256)
void prep_kernel(const int* __restrict__ nodes,
                 const float* __restrict__ uW, const float* __restrict__ iW,
                 const float* __restrict__ aW1, const float* __restrict__ aW2,
                 short* __restrict__ wp, int* __restrict__ owner)
{
    if (blockIdx.x < NBLK_PACK) {
        int i = blockIdx.x * 256 + threadIdx.x;
        float v;
        if (i < 32768)      { int j = i;         int n = j >> 8, k = j & 255; v = iW[k * EN + n]; }
        else if (i < 65536) { int j = i - 32768; int n = j >> 8, k = j & 255; v = uW[k * EN + n]; }
        else if (i < 81920) { int j = i - 65536; int n = j >> 7, k = j & 127; v = aW1[k * EN + n]; }
        else if (i < 98304) { int j = i - 81920; int n = j >> 7, k = j & 127; v = aW1[(128 + k) * EN + n]; }
        else                { int j = i - 98304; int n = j >> 7, k = j & 127; v = aW2[k * EN + n]; }
        wp[i] = (short)f2b(v);
    } else {
        int b = (blockIdx.x - NBLK_PACK) * 256 + threadIdx.x;
        if (b < BB) owner[nodes[b]] = -1;
    }
}

// ---- K2: union kernel: neighs table | nf/npart (+owner max) ; tail-zero of out_embed ----
__global__ __launch_bounds__(256, 4)
void embed_kernel(const int* __restrict__ nodes,
                  const float* __restrict__ u_weight, const float* __restrict__ i_weight,
                  const float* __restrict__ ub, const float* __restrict__ ib,
                  const float* __restrict__ ab1,
                  const short* __restrict__ wp, int* __restrict__ owner,
                  short* __restrict__ ntab, float* __restrict__ out_nf,
                  float* __restrict__ npart, float* __restrict__ out_embed)
{
    __shared__ __align__(16) char smem[33792];   // A-staging (528B x 64 rows); overlaid by outputs
    __shared__ int sNd[64];

    const int tid = threadIdx.x;
    const int l = tid & 63, lr = l & 15, lq = l >> 4, n0 = (tid >> 6) * 32;
    const int kA = lq * 8, nc0 = n0 + lr, nc1 = n0 + 16 + lr;

    if (blockIdx.x < NBLK_NEIGH) {
        // ======== neighs path: ntab[r] = bf16(i_weight[r] @ iW + ib) ========
        const int r0 = blockIdx.x * 64;
        const int nrows = (NI - r0 < 64) ? (NI - r0) : 64;

        for (int task = tid; task < 64 * 32; task += 256) {
            int row = task >> 5, c = task & 31;
            if (row < nrows) {
                const float* src = i_weight + (size_t)(r0 + row) * DK + c * 8;
                float4 f0 = *(const float4*)src;
                float4 f1 = *(const float4*)(src + 4);
                short8 o;
                o[0]=f2b(f0.x); o[1]=f2b(f0.y); o[2]=f2b(f0.z); o[3]=f2b(f0.w);
                o[4]=f2b(f1.x); o[5]=f2b(f1.y); o[6]=f2b(f1.z); o[7]=f2b(f1.w);
                *reinterpret_cast<short8*>(smem + row * 528 + c * 16) = o;
            }
        }
        __syncthreads();

        const short* iWt = wp + OFF_IWT;
        f32x4 acc[4][2];
        #pragma unroll
        for (int m = 0; m < 4; ++m) { acc[m][0] = {0.f,0.f,0.f,0.f}; acc[m][1] = {0.f,0.f,0.f,0.f}; }
        #pragma unroll
        for (int ks = 0; ks < 8; ++ks) {
            int k = ks * 32 + kA;
            short8 w0 = *reinterpret_cast<const short8*>(iWt + nc0 * DK + k);
            short8 w1 = *reinterpret_cast<const short8*>(iWt + nc1 * DK + k);
            #pragma unroll
            for (int m = 0; m < 4; ++m) {
                short8 a = LDROW(smem, 528, m * 16 + lr, k);
                acc[m][0] = MFMA(a, w0, acc[m][0]);
                acc[m][1] = MFMA(a, w1, acc[m][1]);
            }
        }
        __syncthreads();   // all reads of A done; overlay output tile (264B stride)
        {
            float ib0 = ib[nc0], ib1 = ib[nc1];
            #pragma unroll
            for (int m = 0; m < 4; ++m)
                #pragma unroll
                for (int nt = 0; nt < 2; ++nt) {
                    int n = nt ? nc1 : nc0;
                    float bv = nt ? ib1 : ib0;
                    #pragma unroll
                    for (int r = 0; r < 4; ++r) {
                        int row = m * 16 + lq * 4 + r;
                        *reinterpret_cast<short*>(smem + row * 264 + n * 2)
                            = (short)f2b(acc[m][nt][r] + bv);
                    }
                }
        }
        __syncthreads();
        for (int g = tid; g < nrows * 16; g += 256) {
            int row = g >> 4, s = g & 15;
            short8 v = *reinterpret_cast<const short8*>(smem + row * 264 + s * 16);
            *reinterpret_cast<short8*>(ntab + (size_t)(r0 + row) * EN + s * 8) = v;
        }
    } else {
        // ======== nf path: out_nf + npart for 64 batch rows; also owner atomicMax ========
        const int bblk = blockIdx.x - NBLK_NEIGH;
        const int r0 = bblk * 64;
        {
            int bq = bblk * 256 + tid;
            if (bq < BB) atomicMax(&owner[nodes[bq]], bq);
        }
        if (tid < 64) sNd[tid] = nodes[r0 + tid];
        __syncthreads();

        for (int task = tid; task < 64 * 32; task += 256) {
            int row = task >> 5, c = task & 31;
            const float* src = u_weight + (size_t)sNd[row] * DK + c * 8;
            float4 f0 = *(const float4*)src;
            float4 f1 = *(const float4*)(src + 4);
            short8 o;
            o[0]=f2b(f0.x); o[1]=f2b(f0.y); o[2]=f2b(f0.z); o[3]=f2b(f0.w);
            o[4]=f2b(f1.x); o[5]=f2b(f1.y); o[6]=f2b(f1.z); o[7]=f2b(f1.w);
            *reinterpret_cast<short8*>(smem + row * 528 + c * 16) = o;
        }
        __syncthreads();

        const short* uWt   = wp + OFF_UWT;
        const short* aW1Lt = wp + OFF_AW1LT;

        f32x4 acc[4][2];
        #pragma unroll
        for (int m = 0; m < 4; ++m) { acc[m][0] = {0.f,0.f,0.f,0.f}; acc[m][1] = {0.f,0.f,0.f,0.f}; }
        #pragma unroll
        for (int ks = 0; ks < 8; ++ks) {
            int k = ks * 32 + kA;
            short8 w0 = *reinterpret_cast<const short8*>(uWt + nc0 * DK + k);
            short8 w1 = *reinterpret_cast<const short8*>(uWt + nc1 * DK + k);
            #pragma unroll
            for (int m = 0; m < 4; ++m) {
                short8 a = LDROW(smem, 528, m * 16 + lr, k);
                acc[m][0] = MFMA(a, w0, acc[m][0]);
                acc[m][1] = MFMA(a, w1, acc[m][1]);
            }
        }
        __syncthreads();   // A reads done; overlay bf16 nf tile (272B stride)
        {
            float b0v = ub[nc0], b1v = ub[nc1];
            #pragma unroll
            for (int m = 0; m < 4; ++m)
                #pragma unroll
                for (int nt = 0; nt < 2; ++nt) {
                    int n = nt ? nc1 : nc0;
                    float bv = nt ? b1v : b0v;
                    #pragma unroll
                    for (int r = 0; r < 4; ++r) {
                        int row = m * 16 + lq * 4 + r;
                        float v = acc[m][nt][r] + bv;
                        out_nf[(size_t)(r0 + row) * EN + n] = v;
                        *reinterpret_cast<short*>(smem + row * 272 + n * 2) = (short)f2b(v);
                    }
                }
        }
        __syncthreads();

        f32x4 ap[4][2];
        #pragma unroll
        for (int m = 0; m < 4; ++m) { ap[m][0] = {0.f,0.f,0.f,0.f}; ap[m][1] = {0.f,0.f,0.f,0.f}; }
        #pragma unroll
        for (int ks = 0; ks < 4; ++ks) {
            int k = ks * 32 + kA;
            short8 w0 = *reinterpret_cast<const short8*>(aW1Lt + nc0 * EN + k);
            short8 w1 = *reinterpret_cast<const short8*>(aW1Lt + nc1 * EN + k);
            #pragma unroll
            for (int m = 0; m < 4; ++m) {
                short8 a = LDROW(smem, 272, m * 16 + lr, k);
                ap[m][0] = MFMA(a, w0, ap[m][0]);
                ap[m][1] = MFMA(a, w1, ap[m][1]);
            }
        }
        {
            float b0v = ab1[nc0], b1v = ab1[nc1];
            #pragma unroll
            for (int m = 0; m < 4; ++m)
                #pragma unroll
                for (int nt = 0; nt < 2; ++nt) {
                    int n = nt ? nc1 : nc0;
                    float bv = nt ? b1v : b0v;
                    #pragma unroll
                    for (int r = 0; r < 4; ++r) {
                        int row = m * 16 + lq * 4 + r;
                        npart[(size_t)(r0 + row) * EN + n] = ap[m][nt][r] + bv;
                    }
                }
        }
    }

    // ---- tail zero of out_embed (unconditional; attn overwrites batch rows later) ----
    {
        float4* embed4 = (float4*)out_embed;
        const int n16 = NU * EN / 4;
        const int gsz = (NBLK_NEIGH + NBLK_NF) * 256;
        float4 z = {0.f, 0.f, 0.f, 0.f};
        for (int i = blockIdx.x * 256 + tid; i < n16; i += gsz) embed4[i] = z;
    }
}

// ---- K3: attn, 4 batch rows per block; wave w owns batch row b0+w end-to-end ----
__global__ __launch_bounds__(256, 2)
void attn_kernel(const int* __restrict__ nodes, const int* __restrict__ neigh_idx,
                 const float* __restrict__ ab2, const float* __restrict__ aW3,
                 const float* __restrict__ ab3, const short* __restrict__ wp,
                 const short* __restrict__ ntab, const float* __restrict__ npart,
                 const int* __restrict__ owner, float* __restrict__ out_embed)
{
    __shared__ __align__(16) short sNg[96 * 136];  // 26112 B, 272B stride
    __shared__ __align__(16) short sH1[96 * 136];  // 26112 B
    __shared__ float sNpF[512];
    __shared__ float sLogP[4][96];

    const int tid = threadIdx.x;
    const int b0  = blockIdx.x * GGA;
    const int l   = tid & 63, w = tid >> 6;
    const int lr  = l & 15, lq = l >> 4;
    const int n0  = w * 32;
    const int kA  = lq * 8, nc0 = n0 + lr, nc1 = n0 + 16 + lr;

    // stage npart for the 4 b-rows
    sNpF[tid]       = npart[(size_t)b0 * EN + tid];
    sNpF[tid + 256] = npart[(size_t)b0 * EN + 256 + tid];

    // gather: wave w stages its own 24 neighbor rows (256B bf16 each)
    #pragma unroll
    for (int j = 0; j < 6; ++j) {
        int task = j * 64 + l;
        int trow = task >> 4, s = task & 15;
        int idx = neigh_idx[(b0 + w) * TT + trow];
        short8 v = *reinterpret_cast<const short8*>(ntab + (size_t)idx * EN + s * 8);
        *reinterpret_cast<short8*>(reinterpret_cast<char*>(sNg) + (w * 24 + trow) * 272 + s * 16) = v;
    }
    __syncthreads();

    const short* aW1Ut = wp + OFF_AW1UT;
    const short* aW2t  = wp + OFF_AW2T;

    // ---- h1 = relu(neighs @ aW1U + npart), 6 m-tiles x wave's 32-col slice ----
    f32x4 acc[6][2];
    #pragma unroll
    for (int m = 0; m < 6; ++m) { acc[m][0] = {0.f,0.f,0.f,0.f}; acc[m][1] = {0.f,0.f,0.f,0.f}; }
    #pragma unroll
    for (int ks = 0; ks < 4; ++ks) {
        int k = ks * 32 + kA;
        short8 w0 = *reinterpret_cast<const short8*>(aW1Ut + nc0 * EN + k);
        short8 w1 = *reinterpret_cast<const short8*>(aW1Ut + nc1 * EN + k);
        #pragma unroll
        for (int m = 0; m < 6; ++m) {
            short8 a = LDROW(sNg, 272, m * 16 + lr, k);
            acc[m][0] = MFMA(a, w0, acc[m][0]);
            acc[m][1] = MFMA(a, w1, acc[m][1]);
        }
    }
    #pragma unroll
    for (int m = 0; m < 6; ++m) {
        // g = batch-row index of this m-tile's rows; depends only on (m, lq)
        int g = (m == 0) ? 0 : (m == 1) ? ((lq < 2) ? 0 : 1)
              : (m == 2) ? 1 : (m == 3) ? 2 : (m == 4) ? ((lq < 2) ? 2 : 3) : 3;
        #pragma unroll
        for (int nt = 0; nt < 2; ++nt) {
            int n = nt ? nc1 : nc0;
            float np = sNpF[g * EN + n];
            float v0 = fmaxf(acc[m][nt][0] + np, 0.f);
            float v1 = fmaxf(acc[m][nt][1] + np, 0.f);
            float v2 = fmaxf(acc[m][nt][2] + np, 0.f);
            float v3 = fmaxf(acc[m][nt][3] + np, 0.f);
            unsigned int p01 = cvtpk_bf16(v0, v1);
            unsigned int p23 = cvtpk_bf16(v2, v3);
            char* base = reinterpret_cast<char*>(sH1) + (m * 16 + lq * 4) * 272 + n * 2;
            *reinterpret_cast<short*>(base)       = (short)(p01 & 0xFFFF);
            *reinterpret_cast<short*>(base + 272) = (short)(p01 >> 16);
            *reinterpret_cast<short*>(base + 544) = (short)(p23 & 0xFFFF);
            *reinterpret_cast<short*>(base + 816) = (short)(p23 >> 16);
        }
    }
    __syncthreads();

    // ---- h2 = relu(h1 @ aW2 + ab2); logits reduced in-register ----
    #pragma unroll
    for (int m = 0; m < 6; ++m) { acc[m][0] = {0.f,0.f,0.f,0.f}; acc[m][1] = {0.f,0.f,0.f,0.f}; }
    #pragma unroll
    for (int ks = 0; ks < 4; ++ks) {
        int k = ks * 32 + kA;
        short8 w0 = *reinterpret_cast<const short8*>(aW2t + nc0 * EN + k);
        short8 w1 = *reinterpret_cast<const short8*>(aW2t + nc1 * EN + k);
        #pragma unroll
        for (int m = 0; m < 6; ++m) {
            short8 a = LDROW(sH1, 272, m * 16 + lr, k);
            acc[m][0] = MFMA(a, w0, acc[m][0]);
            acc[m][1] = MFMA(a, w1, acc[m][1]);
        }
    }
    {
        float b0v = ab2[nc0], b1v = ab2[nc1];
        float w3a = aW3[nc0], w3b = aW3[nc1];
        #pragma unroll
        for (int m = 0; m < 6; ++m) {
            float lp[4];
            #pragma unroll
            for (int r = 0; r < 4; ++r) {
                float v0 = fmaxf(acc[m][0][r] + b0v, 0.f);
                float v1 = fmaxf(acc[m][1][r] + b1v, 0.f);
                lp[r] = v0 * w3a + v1 * w3b;
            }
            #pragma unroll
            for (int r = 0; r < 4; ++r) {
                float v = lp[r];
                v += __shfl_xor(v, 1, 16);
                v += __shfl_xor(v, 2, 16);
                v += __shfl_xor(v, 4, 16);
                v += __shfl_xor(v, 8, 16);
                if (lr == 0) sLogP[w][m * 16 + lq * 4 + r] = v;
            }
        }
    }
    __syncthreads();

    // ---- per-wave softmax over T=24 for batch row b0+w (no extra barriers) ----
    float lg = -1e30f;
    if (l < TT)
        lg = sLogP[0][w * 24 + l] + sLogP[1][w * 24 + l]
           + sLogP[2][w * 24 + l] + sLogP[3][w * 24 + l] + ab3[0];
    float mx = lg;
    #pragma unroll
    for (int d = 32; d > 0; d >>= 1) mx = fmaxf(mx, __shfl_xor(mx, d, 64));
    float p = (l < TT) ? __expf(lg - mx) : 0.f;
    float s = p;
    #pragma unroll
    for (int d = 32; d > 0; d >>= 1) s += __shfl_xor(s, d, 64);
    float att = p / s;

    // ---- agg + scatter: lane l covers cols l and l+64 of batch row b0+w ----
    {
        float a0 = 0.f, a1 = 0.f;
        #pragma unroll
        for (int t = 0; t < TT; ++t) {
            float wt = __shfl(att, t, 64);
            const char* rbase = reinterpret_cast<const char*>(sNg) + (w * 24 + t) * 272;
            a0 += wt * b2f(*reinterpret_cast<const unsigned short*>(rbase + l * 2));
            a1 += wt * b2f(*reinterpret_cast<const unsigned short*>(rbase + (l + 64) * 2));
        }
        int node = nodes[b0 + w];
        if (owner[node] == b0 + w) {
            out_embed[(size_t)node * EN + l]      = a0;
            out_embed[(size_t)node * EN + 64 + l] = a1;
        }
    }
}

extern "C" void kernel_launch(void* const* d_in, const int* in_sizes, int n_in,
                              void* d_out, int out_size, void* d_ws, size_t ws_size,
                              hipStream_t stream) {
    const int*   nodes     = (const int*)d_in[0];
    const int*   neigh_idx = (const int*)d_in[1];
    const float* u_weight  = (const float*)d_in[2];
    const float* i_weight  = (const float*)d_in[3];
    const float* uW  = (const float*)d_in[4];
    const float* ub  = (const float*)d_in[5];
    const float* iW  = (const float*)d_in[6];
    const float* ib  = (const float*)d_in[7];
    const float* aW1 = (const float*)d_in[8];
    const float* ab1 = (const float*)d_in[9];
    const float* aW2 = (const float*)d_in[10];
    const float* ab2 = (const float*)d_in[11];
    const float* aW3 = (const float*)d_in[12];
    const float* ab3 = (const float*)d_in[13];

    float* out_nf    = (float*)d_out;
    float* out_embed = out_nf + (size_t)BB * EN;

    char*  ws    = (char*)d_ws;
    short* wpack = (short*)(ws + WP_OFF);
    int*   owner = (int*)(ws + OWNER_OFF);
    short* ntab  = (short*)(ws + NTAB_OFF);
    float* npart = (float*)(ws + NPART_OFF);

    prep_kernel<<<NBLK_PACK + 32, 256, 0, stream>>>(nodes, uW, iW, aW1, aW2, wpack, owner);
    embed_kernel<<<NBLK_NEIGH + NBLK_NF, 256, 0, stream>>>(
        nodes, u_weight, i_weight, ub, ib, ab1, wpack, owner, ntab, out_nf, npart, out_embed);
    attn_kernel<<<ATTN_BLKS, 256, 0, stream>>>(nodes, neigh_idx, ab2, aW3, ab3,
                                               wpack, ntab, npart, owner, out_embed);
}